// Round 8
// baseline (450.582 us; speedup 1.0000x reference)
//
#include <hip/hip_runtime.h>

#define E_EDGES 320000
#define NN 20000
#define HID 128
#define TS 136   // LDS T-tile stride (bf16 elems): 272B == 16 mod 128 -> spread banks

typedef __attribute__((ext_vector_type(8))) short short8;
typedef __attribute__((ext_vector_type(4))) float f32x4;
typedef __attribute__((ext_vector_type(8))) unsigned short us8;

__device__ __forceinline__ unsigned short f2b(float f) {
  unsigned u = __builtin_bit_cast(unsigned, f);
  u += 0x7fffu + ((u >> 16) & 1u);
  return (unsigned short)(u >> 16);
}
__device__ __forceinline__ float silu_f(float x) { return x / (1.0f + __expf(-x)); }

// ---------------- workspace zero-init ----------------------------------------
__global__ void zero_k(float* __restrict__ p, int n4) {
  int i = blockIdx.x * 256 + threadIdx.x;
  if (i < n4) reinterpret_cast<float4*>(p)[i] = float4{0.0f, 0.0f, 0.0f, 0.0f};
}

// ---------------- weight prepack: f32 [K][128] -> bf16 MFMA-fragment order ---
// dst[((kt*8 + ntg)*64 + lane)*8 + r] = W[kt*32 + (lane>>4)*8 + r][ntg*16 + (lane&15)]
__global__ void prepack_k(const float* __restrict__ Wce1, const float* __restrict__ Wce2,
                          const float* __restrict__ Ws1,  const float* __restrict__ Ws2,
                          const float* __restrict__ Wpe2, const float* __restrict__ Wpe1,
                          unsigned short* __restrict__ dst) {
  int i = blockIdx.x * 256 + threadIdx.x;          // grid covers exactly 102400
  const float* W; int Ksrc, base;
  if (i < 32768)      { W = Wce1; Ksrc = 256; base = 0; }
  else if (i < 49152) { W = Wce2; Ksrc = 128; base = 32768; }
  else if (i < 65536) { W = Ws1;  Ksrc = 128; base = 49152; }
  else if (i < 81920) { W = Ws2;  Ksrc = 128; base = 65536; }
  else if (i < 98304) { W = Wpe2; Ksrc = 128; base = 81920; }
  else                { W = Wpe1; Ksrc = 18;  base = 98304; }
  int j = i - base;
  int r = j & 7, lane = (j >> 3) & 63, ntg = (j >> 9) & 7, kt = j >> 12;
  int sk = kt * 32 + ((lane >> 4) << 3) + r;
  int sn = (ntg << 4) + (lane & 15);
  float v = (sk < Ksrc) ? W[sk * HID + sn] : 0.0f;
  dst[i] = f2b(v);
}

// ---------------- per-edge geometry + segment-sum atomics + radial table -----
__global__ void edge_geom_k(const int* __restrict__ erow, const int* __restrict__ ecol,
                            const float* __restrict__ coord,
                            float* __restrict__ nf,
                            float* __restrict__ cdn, unsigned short* __restrict__ rad16) {
  int i = blockIdx.x * 256 + threadIdx.x;
  if (i >= E_EDGES) return;
  int r = erow[i], c = ecol[i];
  float dx = coord[r*3+0] - coord[c*3+0];
  float dy = coord[r*3+1] - coord[c*3+1];
  float dz = coord[r*3+2] - coord[c*3+2];
  float r2 = dx*dx + dy*dy + dz*dz;
  float dn = sqrtf(r2);
  float invn = 1.0f / (dn + 1e-8f);
  cdn[i*3+0] = dx*invn; cdn[i*3+1] = dy*invn; cdn[i*3+2] = dz*invn;

  unsigned short rv[16];
  float t = 1.0f;
  #pragma unroll
  for (int s = 0; s < 15; s++) { rv[s] = f2b(__expf(r2 * (-0.5f / t))); t *= 2.25f; }
  rv[15] = 0;
  us8 lo, hi;
  #pragma unroll
  for (int k = 0; k < 8; k++) { lo[k] = rv[k]; hi[k] = rv[8+k]; }
  *reinterpret_cast<us8*>(rad16 + (size_t)i*16)     = lo;
  *reinterpret_cast<us8*>(rad16 + (size_t)i*16 + 8) = hi;

  float inv = 1.0f / dn;
  float w3 = inv*inv*inv, w4 = w3*inv, w5 = w4*inv;
  float* p = nf + r*9;
  unsafeAtomicAdd(p+0, w3*dx); unsafeAtomicAdd(p+1, w3*dy); unsafeAtomicAdd(p+2, w3*dz);
  unsafeAtomicAdd(p+3, w4*dx); unsafeAtomicAdd(p+4, w4*dy); unsafeAtomicAdd(p+5, w4*dz);
  unsafeAtomicAdd(p+6, w5*dx); unsafeAtomicAdd(p+7, w5*dy); unsafeAtomicAdd(p+8, w5*dz);
}

// ---------------- per-node normalize ------------------------------------------
__global__ void node_norm_k(const float* __restrict__ nf, float* __restrict__ nvecs) {
  int n = blockIdx.x * 256 + threadIdx.x;
  if (n >= NN) return;
  #pragma unroll
  for (int a = 0; a < 3; a++) {
    float x = nf[n*9+a*3+0], y = nf[n*9+a*3+1], z = nf[n*9+a*3+2];
    float nm = sqrtf(x*x + y*y + z*z);
    float s = 1.0f / (nm + 1e-8f);
    nvecs[n*9+a*3+0] = x*s; nvecs[n*9+a*3+1] = y*s; nvecs[n*9+a*3+2] = z*s;
  }
}

// ---------------- node-level ce1 halves: Htop = h@Wt + b1, Hbot = h@Wb --------
__global__ __launch_bounds__(256) void node_mlp_k(
    const float* __restrict__ h, const unsigned short* __restrict__ wp,
    const float* __restrict__ b1,
    float* __restrict__ Htop, float* __restrict__ Hbot) {
  const int tid = threadIdx.x, lane = tid & 63, wv = tid >> 6;
  const int cl = lane & 15, kg = lane >> 4;
  const int n0 = (blockIdx.x * 4 + wv) * 32;   // this wave's 32 nodes
  if (n0 >= NN) return;

  #pragma unroll
  for (int half = 0; half < 2; half++) {       // 0: Wt rows 0-127, 1: Wb rows 128-255
    f32x4 acc[2][8];
    #pragma unroll
    for (int nt = 0; nt < 8; nt++) {
      float b = half ? 0.0f : b1[nt*16 + cl];
      acc[0][nt] = f32x4{b,b,b,b}; acc[1][nt] = f32x4{b,b,b,b};
    }
    #pragma unroll
    for (int k4 = 0; k4 < 4; k4++) {
      int kt = half*4 + k4;
      short8 bf[8];
      #pragma unroll
      for (int nt = 0; nt < 8; nt++)
        bf[nt] = *reinterpret_cast<const short8*>(wp + ((kt*8 + nt)*64 + lane)*8);
      #pragma unroll
      for (int rt = 0; rt < 2; rt++) {
        int node = n0 + rt*16 + cl;
        if (node >= NN) node = 0;
        const float* hp = h + (size_t)node * HID + k4*32 + kg*8;
        float4 v0 = *reinterpret_cast<const float4*>(hp);
        float4 v1 = *reinterpret_cast<const float4*>(hp + 4);
        short8 af;
        af[0]=(short)f2b(v0.x); af[1]=(short)f2b(v0.y); af[2]=(short)f2b(v0.z); af[3]=(short)f2b(v0.w);
        af[4]=(short)f2b(v1.x); af[5]=(short)f2b(v1.y); af[6]=(short)f2b(v1.z); af[7]=(short)f2b(v1.w);
        #pragma unroll
        for (int nt = 0; nt < 8; nt++)
          acc[rt][nt] = __builtin_amdgcn_mfma_f32_16x16x32_bf16(af, bf[nt], acc[rt][nt], 0, 0, 0);
      }
    }
    float* dst = half ? Hbot : Htop;
    #pragma unroll
    for (int rt = 0; rt < 2; rt++)
      #pragma unroll
      for (int nt = 0; nt < 8; nt++)
        #pragma unroll
        for (int g = 0; g < 4; g++) {
          int node = n0 + rt*16 + kg*4 + g;
          if (node < NN) dst[(size_t)node * HID + nt*16 + cl] = acc[rt][nt][g];
        }
  }
}

// ---------------- persistent edge kernel: weights in LDS, 1 block/CU ----------
// ce2+s1 B-matrices staged once into LDS (64 KB); A for ce2 gathered directly
// from Htop/Hbot into fragments (no t1 staging); per-wave T tile for layer
// transposes; s2/pe1/pe2 weights from global (L1-hot). Grid-stride, no barriers
// in the main loop.
__global__ __launch_bounds__(256, 1) void edge_mlp_k(
    const int* __restrict__ erow, const int* __restrict__ ecol,
    const float* __restrict__ Htop, const float* __restrict__ Hbot,
    const unsigned short* __restrict__ rad16, const float* __restrict__ nvecs,
    const unsigned short* __restrict__ wp,
    const float* __restrict__ b2,  const float* __restrict__ bs1,
    const float* __restrict__ bs2, const float* __restrict__ bp1,
    const float* __restrict__ bp2,
    const float* __restrict__ watt, const float* __restrict__ batt,
    float* __restrict__ out0, float* __restrict__ chem_o, float* __restrict__ pos_o) {
  __shared__ unsigned short lw[32768];       // ce2 (16384) | s1 (16384), fragment order
  __shared__ unsigned short sT[4][32 * TS];  // per-wave transpose tiles

  const int tid = threadIdx.x, lane = tid & 63, wv = tid >> 6;
  const int cl = lane & 15, kg = lane >> 4;

  // stage ce2+s1 weights (contiguous in wpack at +32768, 32768 bf16)
  for (int i = tid * 8; i < 32768; i += 2048)
    *reinterpret_cast<short8*>(lw + i) = *reinterpret_cast<const short8*>(wp + 32768 + i);
  __syncthreads();

  // per-lane biases (col = nt*16+cl) held in registers for the whole kernel
  float B2[8], BS1[8], BS2[8], BP1[8], BP2[8], WA[8];
  #pragma unroll
  for (int nt = 0; nt < 8; nt++) {
    B2[nt]  = b2 [nt*16 + cl];
    BS1[nt] = bs1[nt*16 + cl];
    BS2[nt] = bs2[nt*16 + cl];
    BP1[nt] = bp1[nt*16 + cl];
    BP2[nt] = bp2[nt*16 + cl];
    WA[nt]  = watt[nt*16 + cl];
  }
  const float ba = batt[0];
  unsigned short* T = sT[wv];

  for (int t = blockIdx.x * 4 + wv; t < E_EDGES / 32; t += 1024) {
    const int e0 = t * 32;
    int er_[2], ec_[2];
    er_[0] = erow[e0 + cl];      ec_[0] = ecol[e0 + cl];
    er_[1] = erow[e0 + 16 + cl]; ec_[1] = ecol[e0 + 16 + cl];

    // ---- ce2: A = silu(Htop[row] + Hbot[col]) gathered straight to fragments
    f32x4 acc[2][8];
    #pragma unroll
    for (int nt = 0; nt < 8; nt++) {
      float b = B2[nt];
      acc[0][nt] = f32x4{b,b,b,b}; acc[1][nt] = f32x4{b,b,b,b};
    }
    #pragma unroll
    for (int kt = 0; kt < 4; kt++) {
      short8 bf[8];
      #pragma unroll
      for (int nt = 0; nt < 8; nt++)
        bf[nt] = *reinterpret_cast<const short8*>(lw + ((kt*8 + nt)*64 + lane)*8);
      #pragma unroll
      for (int rt = 0; rt < 2; rt++) {
        const float* tp = Htop + (size_t)er_[rt] * HID + kt*32 + kg*8;
        const float* bp = Hbot + (size_t)ec_[rt] * HID + kt*32 + kg*8;
        float4 a0 = *reinterpret_cast<const float4*>(tp);
        float4 a1 = *reinterpret_cast<const float4*>(tp + 4);
        float4 c0 = *reinterpret_cast<const float4*>(bp);
        float4 c1 = *reinterpret_cast<const float4*>(bp + 4);
        short8 af;
        af[0]=(short)f2b(silu_f(a0.x+c0.x)); af[1]=(short)f2b(silu_f(a0.y+c0.y));
        af[2]=(short)f2b(silu_f(a0.z+c0.z)); af[3]=(short)f2b(silu_f(a0.w+c0.w));
        af[4]=(short)f2b(silu_f(a1.x+c1.x)); af[5]=(short)f2b(silu_f(a1.y+c1.y));
        af[6]=(short)f2b(silu_f(a1.z+c1.z)); af[7]=(short)f2b(silu_f(a1.w+c1.w));
        #pragma unroll
        for (int nt = 0; nt < 8; nt++)
          acc[rt][nt] = __builtin_amdgcn_mfma_f32_16x16x32_bf16(af, bf[nt], acc[rt][nt], 0, 0, 0);
      }
    }
    #pragma unroll
    for (int rt = 0; rt < 2; rt++)
      #pragma unroll
      for (int nt = 0; nt < 8; nt++)
        #pragma unroll
        for (int g = 0; g < 4; g++) {
          float x = acc[rt][nt][g];
          chem_o[(size_t)(e0 + rt*16 + kg*4 + g) * HID + nt*16 + cl] = x;
          T[(rt*16 + kg*4 + g)*TS + nt*16 + cl] = f2b(x);
        }

    // ---- s1: silu(T @ Ws1 + bs1) -> T (weights in LDS at lw+16384) ----
    #pragma unroll
    for (int nt = 0; nt < 8; nt++) {
      float b = BS1[nt];
      acc[0][nt] = f32x4{b,b,b,b}; acc[1][nt] = f32x4{b,b,b,b};
    }
    #pragma unroll
    for (int kt = 0; kt < 4; kt++) {
      short8 bf[8];
      #pragma unroll
      for (int nt = 0; nt < 8; nt++)
        bf[nt] = *reinterpret_cast<const short8*>(lw + 16384 + ((kt*8 + nt)*64 + lane)*8);
      #pragma unroll
      for (int rt = 0; rt < 2; rt++) {
        short8 af = *reinterpret_cast<const short8*>(T + (rt*16 + cl)*TS + kt*32 + kg*8);
        #pragma unroll
        for (int nt = 0; nt < 8; nt++)
          acc[rt][nt] = __builtin_amdgcn_mfma_f32_16x16x32_bf16(af, bf[nt], acc[rt][nt], 0, 0, 0);
      }
    }
    #pragma unroll
    for (int rt = 0; rt < 2; rt++)
      #pragma unroll
      for (int nt = 0; nt < 8; nt++)
        #pragma unroll
        for (int g = 0; g < 4; g++)
          T[(rt*16 + kg*4 + g)*TS + nt*16 + cl] = f2b(silu_f(acc[rt][nt][g]));

    // ---- s2 -> accS (weights from global, L1-hot) ----
    f32x4 accS[2][8];
    #pragma unroll
    for (int nt = 0; nt < 8; nt++) {
      float b = BS2[nt];
      accS[0][nt] = f32x4{b,b,b,b}; accS[1][nt] = f32x4{b,b,b,b};
    }
    #pragma unroll
    for (int kt = 0; kt < 4; kt++) {
      short8 bf[8];
      #pragma unroll
      for (int nt = 0; nt < 8; nt++)
        bf[nt] = *reinterpret_cast<const short8*>(wp + 65536 + ((kt*8 + nt)*64 + lane)*8);
      #pragma unroll
      for (int rt = 0; rt < 2; rt++) {
        short8 af = *reinterpret_cast<const short8*>(T + (rt*16 + cl)*TS + kt*32 + kg*8);
        #pragma unroll
        for (int nt = 0; nt < 8; nt++)
          accS[rt][nt] = __builtin_amdgcn_mfma_f32_16x16x32_bf16(af, bf[nt], accS[rt][nt], 0, 0, 0);
      }
    }

    // ---- pe1: pin = [nprod(3) | radial(15) | pad] in-register ----
    us8 r0[2], r1[2];
    #pragma unroll
    for (int rt = 0; rt < 2; rt++) {
      r0[rt] = *reinterpret_cast<const us8*>(rad16 + (size_t)(e0 + rt*16 + cl)*16);
      r1[rt] = *reinterpret_cast<const us8*>(rad16 + (size_t)(e0 + rt*16 + cl)*16 + 8);
    }
    float np[2][3];
    if (kg == 0) {
      #pragma unroll
      for (int rt = 0; rt < 2; rt++) {
        int er2 = er_[rt], ec2 = ec_[rt];
        #pragma unroll
        for (int a = 0; a < 3; a++)
          np[rt][a] = nvecs[er2*9+a*3+0]*nvecs[ec2*9+a*3+0]
                    + nvecs[er2*9+a*3+1]*nvecs[ec2*9+a*3+1]
                    + nvecs[er2*9+a*3+2]*nvecs[ec2*9+a*3+2];
      }
    }
    #pragma unroll
    for (int nt = 0; nt < 8; nt++) {
      float b = BP1[nt];
      acc[0][nt] = f32x4{b,b,b,b}; acc[1][nt] = f32x4{b,b,b,b};
    }
    {
      short8 bf[8];
      #pragma unroll
      for (int nt = 0; nt < 8; nt++)
        bf[nt] = *reinterpret_cast<const short8*>(wp + 98304 + (nt*64 + lane)*8);
      #pragma unroll
      for (int rt = 0; rt < 2; rt++) {
        short8 af;
        if (kg == 0) {
          af[0]=(short)f2b(np[rt][0]); af[1]=(short)f2b(np[rt][1]); af[2]=(short)f2b(np[rt][2]);
          af[3]=(short)r0[rt][0]; af[4]=(short)r0[rt][1]; af[5]=(short)r0[rt][2];
          af[6]=(short)r0[rt][3]; af[7]=(short)r0[rt][4];
        } else if (kg == 1) {
          af[0]=(short)r0[rt][5]; af[1]=(short)r0[rt][6]; af[2]=(short)r0[rt][7];
          af[3]=(short)r1[rt][0]; af[4]=(short)r1[rt][1]; af[5]=(short)r1[rt][2];
          af[6]=(short)r1[rt][3]; af[7]=(short)r1[rt][4];
        } else if (kg == 2) {
          af[0]=(short)r1[rt][5]; af[1]=(short)r1[rt][6];
          af[2]=0; af[3]=0; af[4]=0; af[5]=0; af[6]=0; af[7]=0;
        } else {
          af[0]=0; af[1]=0; af[2]=0; af[3]=0; af[4]=0; af[5]=0; af[6]=0; af[7]=0;
        }
        #pragma unroll
        for (int nt = 0; nt < 8; nt++)
          acc[rt][nt] = __builtin_amdgcn_mfma_f32_16x16x32_bf16(af, bf[nt], acc[rt][nt], 0, 0, 0);
      }
    }
    #pragma unroll
    for (int rt = 0; rt < 2; rt++)
      #pragma unroll
      for (int nt = 0; nt < 8; nt++)
        #pragma unroll
        for (int g = 0; g < 4; g++)
          T[(rt*16 + kg*4 + g)*TS + nt*16 + cl] = f2b(silu_f(acc[rt][nt][g]));

    // ---- pe2 in two N-halves; fold pos write + o=s2*pos + att partial ----
    float ps[2][4] = {{0,0,0,0},{0,0,0,0}};
    #pragma unroll
    for (int half = 0; half < 2; half++) {
      f32x4 ph[2][4];
      #pragma unroll
      for (int n4 = 0; n4 < 4; n4++) {
        float b = BP2[half*4 + n4];
        ph[0][n4] = f32x4{b,b,b,b}; ph[1][n4] = f32x4{b,b,b,b};
      }
      #pragma unroll
      for (int kt = 0; kt < 4; kt++) {
        short8 bf[4];
        #pragma unroll
        for (int n4 = 0; n4 < 4; n4++)
          bf[n4] = *reinterpret_cast<const short8*>(wp + 81920 + ((kt*8 + half*4 + n4)*64 + lane)*8);
        #pragma unroll
        for (int rt = 0; rt < 2; rt++) {
          short8 af = *reinterpret_cast<const short8*>(T + (rt*16 + cl)*TS + kt*32 + kg*8);
          #pragma unroll
          for (int n4 = 0; n4 < 4; n4++)
            ph[rt][n4] = __builtin_amdgcn_mfma_f32_16x16x32_bf16(af, bf[n4], ph[rt][n4], 0, 0, 0);
        }
      }
      #pragma unroll
      for (int rt = 0; rt < 2; rt++)
        #pragma unroll
        for (int n4 = 0; n4 < 4; n4++) {
          int nt = half*4 + n4;
          float wa = WA[nt];
          #pragma unroll
          for (int g = 0; g < 4; g++) {
            float p = ph[rt][n4][g];
            pos_o[(size_t)(e0 + rt*16 + kg*4 + g) * HID + nt*16 + cl] = p;
            float o = accS[rt][nt][g] * p;
            accS[rt][nt][g] = o;
            ps[rt][g] += o * wa;
          }
        }
    }

    // ---- attention + final out ----
    #pragma unroll
    for (int rt = 0; rt < 2; rt++)
      #pragma unroll
      for (int g = 0; g < 4; g++) {
        float s = ps[rt][g];
        s += __shfl_xor(s, 1);
        s += __shfl_xor(s, 2);
        s += __shfl_xor(s, 4);
        s += __shfl_xor(s, 8);
        float av = 1.0f / (1.0f + __expf(-(s + ba)));
        #pragma unroll
        for (int nt = 0; nt < 8; nt++)
          out0[(size_t)(e0 + rt*16 + kg*4 + g) * HID + nt*16 + cl] = accS[rt][nt][g] * av;
      }
  }
}

// ---------------- launcher ----------------------------------------------------
extern "C" void kernel_launch(void* const* d_in, const int* in_sizes, int n_in,
                              void* d_out, int out_size, void* d_ws, size_t ws_size,
                              hipStream_t stream) {
  (void)in_sizes; (void)n_in; (void)out_size; (void)ws_size;
  const float* h     = (const float*)d_in[0];
  const float* coord = (const float*)d_in[1];
  const int*   edges = (const int*)d_in[2];
  const float* W_ce1 = (const float*)d_in[3];  const float* b_ce1 = (const float*)d_in[4];
  const float* W_ce2 = (const float*)d_in[5];  const float* b_ce2 = (const float*)d_in[6];
  const float* W_pe1 = (const float*)d_in[7];  const float* b_pe1 = (const float*)d_in[8];
  const float* W_pe2 = (const float*)d_in[9];  const float* b_pe2 = (const float*)d_in[10];
  const float* W_s1  = (const float*)d_in[11]; const float* b_s1  = (const float*)d_in[12];
  const float* W_s2  = (const float*)d_in[13]; const float* b_s2  = (const float*)d_in[14];
  const float* W_att = (const float*)d_in[15]; const float* b_att = (const float*)d_in[16];

  float* out  = (float*)d_out;
  float* chem = out  + (size_t)E_EDGES * HID;
  float* pos  = chem + (size_t)E_EDGES * HID;
  float* cdn  = pos  + (size_t)E_EDGES * HID;

  char* ws = (char*)d_ws;
  float* nf    = (float*)(ws);                         // NN*9 f32      (720,000 B)
  float* nvecs = (float*)(ws + 720000);                // NN*9 f32      (720,000 B)
  float* Htop  = (float*)(ws + 1440000);               // NN*128 f32    (10,240,000 B)
  float* Hbot  = (float*)(ws + 11680000);              // NN*128 f32    (10,240,000 B)
  unsigned short* wpack = (unsigned short*)(ws + 21920000);  // 102400 bf16 (204,800 B)
  unsigned short* rad16 = (unsigned short*)(ws + 22124800);  // E*16 bf16   (10,240,000 B)

  zero_k<<<(NN * 9 / 4 + 255) / 256, 256, 0, stream>>>(nf, NN * 9 / 4);
  prepack_k<<<400, 256, 0, stream>>>(W_ce1, W_ce2, W_s1, W_s2, W_pe2, W_pe1, wpack);
  node_mlp_k<<<(NN + 127) / 128, 256, 0, stream>>>(h, wpack, b_ce1, Htop, Hbot);
  edge_geom_k<<<E_EDGES / 256, 256, 0, stream>>>(edges, edges + E_EDGES, coord,
                                                 nf, cdn, rad16);
  node_norm_k<<<(NN + 255) / 256, 256, 0, stream>>>(nf, nvecs);
  edge_mlp_k<<<256, 256, 0, stream>>>(edges, edges + E_EDGES, Htop, Hbot,
                                      rad16, nvecs, wpack,
                                      b_ce2, b_s1, b_s2, b_pe1, b_pe2,
                                      W_att, b_att, out, chem, pos);
}

// Round 9
// 421.224 us; speedup vs baseline: 1.0697x; 1.0697x over previous
//
#include <hip/hip_runtime.h>

#define E_EDGES 320000
#define NN 20000
#define HID 128
#define TS 136   // LDS T-tile stride (bf16 elems): 272B == 16 mod 128 -> spread banks

typedef __attribute__((ext_vector_type(8))) short short8;
typedef __attribute__((ext_vector_type(4))) float f32x4;
typedef __attribute__((ext_vector_type(8))) unsigned short us8;

__device__ __forceinline__ unsigned short f2b(float f) {
  unsigned u = __builtin_bit_cast(unsigned, f);
  u += 0x7fffu + ((u >> 16) & 1u);
  return (unsigned short)(u >> 16);
}
__device__ __forceinline__ float silu_f(float x) { return x / (1.0f + __expf(-x)); }

// ---------------- workspace zero-init ----------------------------------------
__global__ void zero_k(float* __restrict__ p, int n4) {
  int i = blockIdx.x * 256 + threadIdx.x;
  if (i < n4) reinterpret_cast<float4*>(p)[i] = float4{0.0f, 0.0f, 0.0f, 0.0f};
}

// ---------------- weight prepack: f32 [K][128] -> bf16 MFMA-fragment order ---
// dst[((kt*8 + ntg)*64 + lane)*8 + r] = W[kt*32 + (lane>>4)*8 + r][ntg*16 + (lane&15)]
__global__ void prepack_k(const float* __restrict__ Wce1, const float* __restrict__ Wce2,
                          const float* __restrict__ Ws1,  const float* __restrict__ Ws2,
                          const float* __restrict__ Wpe2, const float* __restrict__ Wpe1,
                          unsigned short* __restrict__ dst) {
  int i = blockIdx.x * 256 + threadIdx.x;          // grid covers exactly 102400
  const float* W; int Ksrc, base;
  if (i < 32768)      { W = Wce1; Ksrc = 256; base = 0; }
  else if (i < 49152) { W = Wce2; Ksrc = 128; base = 32768; }
  else if (i < 65536) { W = Ws1;  Ksrc = 128; base = 49152; }
  else if (i < 81920) { W = Ws2;  Ksrc = 128; base = 65536; }
  else if (i < 98304) { W = Wpe2; Ksrc = 128; base = 81920; }
  else                { W = Wpe1; Ksrc = 18;  base = 98304; }
  int j = i - base;
  int r = j & 7, lane = (j >> 3) & 63, ntg = (j >> 9) & 7, kt = j >> 12;
  int sk = kt * 32 + ((lane >> 4) << 3) + r;
  int sn = (ntg << 4) + (lane & 15);
  float v = (sk < Ksrc) ? W[sk * HID + sn] : 0.0f;
  dst[i] = f2b(v);
}

// ---------------- per-edge geometry + segment-sum atomics + radial table -----
__global__ void edge_geom_k(const int* __restrict__ erow, const int* __restrict__ ecol,
                            const float* __restrict__ coord,
                            float* __restrict__ nf,
                            float* __restrict__ cdn, unsigned short* __restrict__ rad16) {
  int i = blockIdx.x * 256 + threadIdx.x;
  if (i >= E_EDGES) return;
  int r = erow[i], c = ecol[i];
  float dx = coord[r*3+0] - coord[c*3+0];
  float dy = coord[r*3+1] - coord[c*3+1];
  float dz = coord[r*3+2] - coord[c*3+2];
  float r2 = dx*dx + dy*dy + dz*dz;
  float dn = sqrtf(r2);
  float invn = 1.0f / (dn + 1e-8f);
  cdn[i*3+0] = dx*invn; cdn[i*3+1] = dy*invn; cdn[i*3+2] = dz*invn;

  unsigned short rv[16];
  float t = 1.0f;
  #pragma unroll
  for (int s = 0; s < 15; s++) { rv[s] = f2b(__expf(r2 * (-0.5f / t))); t *= 2.25f; }
  rv[15] = 0;
  us8 lo, hi;
  #pragma unroll
  for (int k = 0; k < 8; k++) { lo[k] = rv[k]; hi[k] = rv[8+k]; }
  *reinterpret_cast<us8*>(rad16 + (size_t)i*16)     = lo;
  *reinterpret_cast<us8*>(rad16 + (size_t)i*16 + 8) = hi;

  float inv = 1.0f / dn;
  float w3 = inv*inv*inv, w4 = w3*inv, w5 = w4*inv;
  float* p = nf + r*9;
  unsafeAtomicAdd(p+0, w3*dx); unsafeAtomicAdd(p+1, w3*dy); unsafeAtomicAdd(p+2, w3*dz);
  unsafeAtomicAdd(p+3, w4*dx); unsafeAtomicAdd(p+4, w4*dy); unsafeAtomicAdd(p+5, w4*dz);
  unsafeAtomicAdd(p+6, w5*dx); unsafeAtomicAdd(p+7, w5*dy); unsafeAtomicAdd(p+8, w5*dz);
}

// ---------------- per-node normalize ------------------------------------------
__global__ void node_norm_k(const float* __restrict__ nf, float* __restrict__ nvecs) {
  int n = blockIdx.x * 256 + threadIdx.x;
  if (n >= NN) return;
  #pragma unroll
  for (int a = 0; a < 3; a++) {
    float x = nf[n*9+a*3+0], y = nf[n*9+a*3+1], z = nf[n*9+a*3+2];
    float nm = sqrtf(x*x + y*y + z*z);
    float s = 1.0f / (nm + 1e-8f);
    nvecs[n*9+a*3+0] = x*s; nvecs[n*9+a*3+1] = y*s; nvecs[n*9+a*3+2] = z*s;
  }
}

// ---------------- node-level ce1 halves: Htop = h@Wt + b1, Hbot = h@Wb --------
__global__ __launch_bounds__(256) void node_mlp_k(
    const float* __restrict__ h, const unsigned short* __restrict__ wp,
    const float* __restrict__ b1,
    float* __restrict__ Htop, float* __restrict__ Hbot) {
  const int tid = threadIdx.x, lane = tid & 63, wv = tid >> 6;
  const int cl = lane & 15, kg = lane >> 4;
  const int n0 = (blockIdx.x * 4 + wv) * 32;   // this wave's 32 nodes
  if (n0 >= NN) return;

  #pragma unroll
  for (int half = 0; half < 2; half++) {       // 0: Wt rows 0-127, 1: Wb rows 128-255
    f32x4 acc[2][8];
    #pragma unroll
    for (int nt = 0; nt < 8; nt++) {
      float b = half ? 0.0f : b1[nt*16 + cl];
      acc[0][nt] = f32x4{b,b,b,b}; acc[1][nt] = f32x4{b,b,b,b};
    }
    #pragma unroll
    for (int k4 = 0; k4 < 4; k4++) {
      int kt = half*4 + k4;
      short8 bf[8];
      #pragma unroll
      for (int nt = 0; nt < 8; nt++)
        bf[nt] = *reinterpret_cast<const short8*>(wp + ((kt*8 + nt)*64 + lane)*8);
      #pragma unroll
      for (int rt = 0; rt < 2; rt++) {
        int node = n0 + rt*16 + cl;
        if (node >= NN) node = 0;
        const float* hp = h + (size_t)node * HID + k4*32 + kg*8;
        float4 v0 = *reinterpret_cast<const float4*>(hp);
        float4 v1 = *reinterpret_cast<const float4*>(hp + 4);
        short8 af;
        af[0]=(short)f2b(v0.x); af[1]=(short)f2b(v0.y); af[2]=(short)f2b(v0.z); af[3]=(short)f2b(v0.w);
        af[4]=(short)f2b(v1.x); af[5]=(short)f2b(v1.y); af[6]=(short)f2b(v1.z); af[7]=(short)f2b(v1.w);
        #pragma unroll
        for (int nt = 0; nt < 8; nt++)
          acc[rt][nt] = __builtin_amdgcn_mfma_f32_16x16x32_bf16(af, bf[nt], acc[rt][nt], 0, 0, 0);
      }
    }
    float* dst = half ? Hbot : Htop;
    #pragma unroll
    for (int rt = 0; rt < 2; rt++)
      #pragma unroll
      for (int nt = 0; nt < 8; nt++)
        #pragma unroll
        for (int g = 0; g < 4; g++) {
          int node = n0 + rt*16 + kg*4 + g;
          if (node < NN) dst[(size_t)node * HID + nt*16 + cl] = acc[rt][nt][g];
        }
  }
}

// ---------------- merged edge kernel v3: 16 edges/wave, occupancy-first -------
// No persistence, no weight staging (weights L1/L2-hot), biases reloaded per
// layer (L1-hot), per-wave 16x136 T-tile (4.4KB). Target: VGPR<=128, 16 waves/CU.
__global__ __launch_bounds__(256, 4) void edge_mlp_k(
    const int* __restrict__ erow, const int* __restrict__ ecol,
    const float* __restrict__ Htop, const float* __restrict__ Hbot,
    const unsigned short* __restrict__ rad16, const float* __restrict__ nvecs,
    const unsigned short* __restrict__ wp,
    const float* __restrict__ b2,  const float* __restrict__ bs1,
    const float* __restrict__ bs2, const float* __restrict__ bp1,
    const float* __restrict__ bp2,
    const float* __restrict__ watt, const float* __restrict__ batt,
    float* __restrict__ out0, float* __restrict__ chem_o, float* __restrict__ pos_o) {
  __shared__ unsigned short sT[4][16 * TS];
  const int tid = threadIdx.x, lane = tid & 63, wv = tid >> 6;
  const int cl = lane & 15, kg = lane >> 4;
  const int e0 = (blockIdx.x * 4 + wv) * 16;
  unsigned short* T = sT[wv];

  const int er_ = erow[e0 + cl];
  const int ec_ = ecol[e0 + cl];

  // ---- ce2: A = silu(Htop[row] + Hbot[col]) gathered straight to fragments --
  f32x4 acc[8];
  #pragma unroll
  for (int nt = 0; nt < 8; nt++) {
    float b = b2[nt*16 + cl];
    acc[nt] = f32x4{b,b,b,b};
  }
  #pragma unroll
  for (int kt = 0; kt < 4; kt++) {
    const float* tp = Htop + (size_t)er_ * HID + kt*32 + kg*8;
    const float* bp = Hbot + (size_t)ec_ * HID + kt*32 + kg*8;
    float4 a0 = *reinterpret_cast<const float4*>(tp);
    float4 a1 = *reinterpret_cast<const float4*>(tp + 4);
    float4 c0 = *reinterpret_cast<const float4*>(bp);
    float4 c1 = *reinterpret_cast<const float4*>(bp + 4);
    short8 af;
    af[0]=(short)f2b(silu_f(a0.x+c0.x)); af[1]=(short)f2b(silu_f(a0.y+c0.y));
    af[2]=(short)f2b(silu_f(a0.z+c0.z)); af[3]=(short)f2b(silu_f(a0.w+c0.w));
    af[4]=(short)f2b(silu_f(a1.x+c1.x)); af[5]=(short)f2b(silu_f(a1.y+c1.y));
    af[6]=(short)f2b(silu_f(a1.z+c1.z)); af[7]=(short)f2b(silu_f(a1.w+c1.w));
    #pragma unroll
    for (int nt = 0; nt < 8; nt++) {
      short8 bf = *reinterpret_cast<const short8*>(wp + 32768 + ((kt*8 + nt)*64 + lane)*8);
      acc[nt] = __builtin_amdgcn_mfma_f32_16x16x32_bf16(af, bf, acc[nt], 0, 0, 0);
    }
  }
  #pragma unroll
  for (int nt = 0; nt < 8; nt++)
    #pragma unroll
    for (int g = 0; g < 4; g++) {
      float x = acc[nt][g];
      chem_o[(size_t)(e0 + kg*4 + g) * HID + nt*16 + cl] = x;
      T[(kg*4 + g)*TS + nt*16 + cl] = f2b(x);
    }

  // ---- s1: silu(T @ Ws1 + bs1) -> T ----
  #pragma unroll
  for (int nt = 0; nt < 8; nt++) {
    float b = bs1[nt*16 + cl];
    acc[nt] = f32x4{b,b,b,b};
  }
  #pragma unroll
  for (int kt = 0; kt < 4; kt++) {
    short8 af = *reinterpret_cast<const short8*>(T + cl*TS + kt*32 + kg*8);
    #pragma unroll
    for (int nt = 0; nt < 8; nt++) {
      short8 bf = *reinterpret_cast<const short8*>(wp + 49152 + ((kt*8 + nt)*64 + lane)*8);
      acc[nt] = __builtin_amdgcn_mfma_f32_16x16x32_bf16(af, bf, acc[nt], 0, 0, 0);
    }
  }
  #pragma unroll
  for (int nt = 0; nt < 8; nt++)
    #pragma unroll
    for (int g = 0; g < 4; g++)
      T[(kg*4 + g)*TS + nt*16 + cl] = f2b(silu_f(acc[nt][g]));

  // ---- s2 -> accS (held) ----
  f32x4 accS[8];
  #pragma unroll
  for (int nt = 0; nt < 8; nt++) {
    float b = bs2[nt*16 + cl];
    accS[nt] = f32x4{b,b,b,b};
  }
  #pragma unroll
  for (int kt = 0; kt < 4; kt++) {
    short8 af = *reinterpret_cast<const short8*>(T + cl*TS + kt*32 + kg*8);
    #pragma unroll
    for (int nt = 0; nt < 8; nt++) {
      short8 bf = *reinterpret_cast<const short8*>(wp + 65536 + ((kt*8 + nt)*64 + lane)*8);
      accS[nt] = __builtin_amdgcn_mfma_f32_16x16x32_bf16(af, bf, accS[nt], 0, 0, 0);
    }
  }

  // ---- pe1: pin = [nprod(3) | radial(15) | pad] in-register ----
  us8 r0 = *reinterpret_cast<const us8*>(rad16 + (size_t)(e0 + cl)*16);
  us8 r1 = *reinterpret_cast<const us8*>(rad16 + (size_t)(e0 + cl)*16 + 8);
  float np[3];
  if (kg == 0) {
    #pragma unroll
    for (int a = 0; a < 3; a++)
      np[a] = nvecs[er_*9+a*3+0]*nvecs[ec_*9+a*3+0]
            + nvecs[er_*9+a*3+1]*nvecs[ec_*9+a*3+1]
            + nvecs[er_*9+a*3+2]*nvecs[ec_*9+a*3+2];
  }
  #pragma unroll
  for (int nt = 0; nt < 8; nt++) {
    float b = bp1[nt*16 + cl];
    acc[nt] = f32x4{b,b,b,b};
  }
  {
    short8 af;
    if (kg == 0) {
      af[0]=(short)f2b(np[0]); af[1]=(short)f2b(np[1]); af[2]=(short)f2b(np[2]);
      af[3]=(short)r0[0]; af[4]=(short)r0[1]; af[5]=(short)r0[2];
      af[6]=(short)r0[3]; af[7]=(short)r0[4];
    } else if (kg == 1) {
      af[0]=(short)r0[5]; af[1]=(short)r0[6]; af[2]=(short)r0[7];
      af[3]=(short)r1[0]; af[4]=(short)r1[1]; af[5]=(short)r1[2];
      af[6]=(short)r1[3]; af[7]=(short)r1[4];
    } else if (kg == 2) {
      af[0]=(short)r1[5]; af[1]=(short)r1[6];
      af[2]=0; af[3]=0; af[4]=0; af[5]=0; af[6]=0; af[7]=0;
    } else {
      af[0]=0; af[1]=0; af[2]=0; af[3]=0; af[4]=0; af[5]=0; af[6]=0; af[7]=0;
    }
    #pragma unroll
    for (int nt = 0; nt < 8; nt++) {
      short8 bf = *reinterpret_cast<const short8*>(wp + 98304 + (nt*64 + lane)*8);
      acc[nt] = __builtin_amdgcn_mfma_f32_16x16x32_bf16(af, bf, acc[nt], 0, 0, 0);
    }
  }
  #pragma unroll
  for (int nt = 0; nt < 8; nt++)
    #pragma unroll
    for (int g = 0; g < 4; g++)
      T[(kg*4 + g)*TS + nt*16 + cl] = f2b(silu_f(acc[nt][g]));

  // ---- pe2 in two N-halves; fold pos write + o=s2*pos + att partial ----
  float ps[4] = {0,0,0,0};
  #pragma unroll
  for (int half = 0; half < 2; half++) {
    f32x4 ph[4];
    #pragma unroll
    for (int n4 = 0; n4 < 4; n4++) {
      float b = bp2[(half*4 + n4)*16 + cl];
      ph[n4] = f32x4{b,b,b,b};
    }
    #pragma unroll
    for (int kt = 0; kt < 4; kt++) {
      short8 af = *reinterpret_cast<const short8*>(T + cl*TS + kt*32 + kg*8);
      #pragma unroll
      for (int n4 = 0; n4 < 4; n4++) {
        short8 bf = *reinterpret_cast<const short8*>(wp + 81920 + ((kt*8 + half*4 + n4)*64 + lane)*8);
        ph[n4] = __builtin_amdgcn_mfma_f32_16x16x32_bf16(af, bf, ph[n4], 0, 0, 0);
      }
    }
    #pragma unroll
    for (int n4 = 0; n4 < 4; n4++) {
      int nt = half*4 + n4;
      float wa = watt[nt*16 + cl];
      #pragma unroll
      for (int g = 0; g < 4; g++) {
        float p = ph[n4][g];
        pos_o[(size_t)(e0 + kg*4 + g) * HID + nt*16 + cl] = p;
        float o = accS[nt][g] * p;
        accS[nt][g] = o;
        ps[g] += o * wa;
      }
    }
  }

  // ---- attention + final out ----
  float ba = batt[0];
  #pragma unroll
  for (int g = 0; g < 4; g++) {
    float s = ps[g];
    s += __shfl_xor(s, 1);
    s += __shfl_xor(s, 2);
    s += __shfl_xor(s, 4);
    s += __shfl_xor(s, 8);
    float av = 1.0f / (1.0f + __expf(-(s + ba)));
    #pragma unroll
    for (int nt = 0; nt < 8; nt++)
      out0[(size_t)(e0 + kg*4 + g) * HID + nt*16 + cl] = accS[nt][g] * av;
  }
}

// ---------------- launcher ----------------------------------------------------
extern "C" void kernel_launch(void* const* d_in, const int* in_sizes, int n_in,
                              void* d_out, int out_size, void* d_ws, size_t ws_size,
                              hipStream_t stream) {
  (void)in_sizes; (void)n_in; (void)out_size; (void)ws_size;
  const float* h     = (const float*)d_in[0];
  const float* coord = (const float*)d_in[1];
  const int*   edges = (const int*)d_in[2];
  const float* W_ce1 = (const float*)d_in[3];  const float* b_ce1 = (const float*)d_in[4];
  const float* W_ce2 = (const float*)d_in[5];  const float* b_ce2 = (const float*)d_in[6];
  const float* W_pe1 = (const float*)d_in[7];  const float* b_pe1 = (const float*)d_in[8];
  const float* W_pe2 = (const float*)d_in[9];  const float* b_pe2 = (const float*)d_in[10];
  const float* W_s1  = (const float*)d_in[11]; const float* b_s1  = (const float*)d_in[12];
  const float* W_s2  = (const float*)d_in[13]; const float* b_s2  = (const float*)d_in[14];
  const float* W_att = (const float*)d_in[15]; const float* b_att = (const float*)d_in[16];

  float* out  = (float*)d_out;
  float* chem = out  + (size_t)E_EDGES * HID;
  float* pos  = chem + (size_t)E_EDGES * HID;
  float* cdn  = pos  + (size_t)E_EDGES * HID;

  char* ws = (char*)d_ws;
  float* nf    = (float*)(ws);                         // NN*9 f32      (720,000 B)
  float* nvecs = (float*)(ws + 720000);                // NN*9 f32      (720,000 B)
  float* Htop  = (float*)(ws + 1440000);               // NN*128 f32    (10,240,000 B)
  float* Hbot  = (float*)(ws + 11680000);              // NN*128 f32    (10,240,000 B)
  unsigned short* wpack = (unsigned short*)(ws + 21920000);  // 102400 bf16 (204,800 B)
  unsigned short* rad16 = (unsigned short*)(ws + 22124800);  // E*16 bf16   (10,240,000 B)

  zero_k<<<(NN * 9 / 4 + 255) / 256, 256, 0, stream>>>(nf, NN * 9 / 4);
  prepack_k<<<400, 256, 0, stream>>>(W_ce1, W_ce2, W_s1, W_s2, W_pe2, W_pe1, wpack);
  node_mlp_k<<<(NN + 127) / 128, 256, 0, stream>>>(h, wpack, b_ce1, Htop, Hbot);
  edge_geom_k<<<E_EDGES / 256, 256, 0, stream>>>(edges, edges + E_EDGES, coord,
                                                 nf, cdn, rad16);
  node_norm_k<<<(NN + 255) / 256, 256, 0, stream>>>(nf, nvecs);
  edge_mlp_k<<<E_EDGES / 64, 256, 0, stream>>>(edges, edges + E_EDGES, Htop, Hbot,
                                               rad16, nvecs, wpack,
                                               b_ce2, b_s1, b_s2, b_pe1, b_pe2,
                                               W_att, b_att, out, chem, pos);
}